// Round 4
// baseline (146.051 us; speedup 1.0000x reference)
//
#include <hip/hip_runtime.h>

// Modulated deformable conv2d, fp32 in/out, bf16 MFMA core.
// B=4, C=64, H=W=128, O=64, K=3x3, stride=1, pad=1, dil=1, og=1, groups=1.
//
// Round 9: round-8 ring had a slot collision (issue of tap k+3 into slot
// (k+3)%3 == k%3 clobbered tap k before its blend -> absmax 3.05). Fix:
// blend-then-issue. Iteration k: blend slot s=k%3 -> A-frag, THEN reload
// slot s with tap k+3 (register dep keeps order), then MFMA. 12 gather
// loads in flight per wave during MFMA; ~48/SIMD at 4 waves/SIMD.
//  - __launch_bounds__(512,4): <=128 VGPR (ring 48 + acc 16 + scalars 27).
//  - XCD-aware bijective block swizzle (grid 1024): L2-resident gathers.
// Fragment layouts (m89/m120-verified): A[m=lane&15][k=quad*8+j],
// B[k=quad*8+j][n=lane&15], D[row=quad*4+reg][col=lane&15].

#define BB 4
#define CC 64
#define HH 128
#define WW 128
#define OO 64
#define KHW 3
#define KK 9
#define HW (HH * WW)

typedef __bf16 bf16_t;
typedef bf16_t bf16x8 __attribute__((ext_vector_type(8)));
typedef float f32x4 __attribute__((ext_vector_type(4)));

// ---- prep: x (NCHW fp32) -> xt (NHWC bf16)  +  weight -> B-fragment bf16 ----
__global__ __launch_bounds__(256) void prep_kernel(const float* __restrict__ x,
                                                   bf16_t* __restrict__ xt,
                                                   const float* __restrict__ w,
                                                   bf16_t* __restrict__ wf) {
    __shared__ float tile[64 * 65];
    const int t = threadIdx.x;
    if (blockIdx.x < BB * 256) {
        const int b  = blockIdx.x >> 8;
        const int p0 = (blockIdx.x & 255) << 6;
#pragma unroll
        for (int i = 0; i < 16; ++i) {
            int c = i * 4 + (t >> 6);
            int p = t & 63;
            tile[c * 65 + p] = x[(b * CC + c) * HW + p0 + p];  // coalesced
        }
        __syncthreads();
#pragma unroll
        for (int i = 0; i < 16; ++i) {
            int p = i * 4 + (t >> 6);
            int c = t & 63;
            xt[(size_t)((b * HW) + p0 + p) * CC + c] = (bf16_t)tile[c * 65 + p];
        }
    } else {
        // wf element index: ((tap*2+q)*4+nt)*64*8 + lane*8 + j
        //   holds W[o = nt*16 + (lane&15)][c = q*32 + (lane>>4)*8 + j][tap]
        int i = (blockIdx.x - BB * 256) * 256 + t;
        if (i >= OO * CC * KK) return;
        int j    = i & 7;
        int lane = (i >> 3) & 63;
        int nt   = (i >> 9) & 3;
        int q    = (i >> 11) & 1;
        int k    = i >> 12;
        int o = nt * 16 + (lane & 15);
        int c = q * 32 + ((lane >> 4) << 3) + j;
        wf[i] = (bf16_t)w[(o * CC + c) * KK + k];
    }
}

__global__ __launch_bounds__(512, 4) void deform_conv_mfma(
    const bf16_t* __restrict__ xt, const float* __restrict__ offset,
    const float* __restrict__ mask, const bf16x8* __restrict__ wf,
    const float* __restrict__ bias, float* __restrict__ out) {
    const int t  = threadIdx.x;
    // XCD-aware bijective swizzle: grid = 1024 = 8 * 128.
    const int wg = (blockIdx.x & 7) * ((BB * 256) >> 3) + (blockIdx.x >> 3);
    const int b     = wg >> 8;
    const int p0    = (wg & 255) << 6;          // 64-pixel group
    const int lane  = t & 63;
    const int wv    = t >> 6;                   // 0..7
    const int strip = wv >> 1;                  // 0..3: 16-pixel strip
    const int q     = wv & 1;                   // K-half: ch q*32..q*32+31
    const int m0    = strip << 4;
    const int col   = lane & 15;                // A-row m == pixel in strip
    const int quad  = lane >> 4;
    const int rem   = p0 + m0 + col;            // this lane's pixel
    const int ho    = rem >> 7;
    const int wo    = rem & (WW - 1);
    const int cb    = q * 32 + (quad << 3);     // this lane's 8-ch slot

    const bf16_t* xb  = xt + (size_t)b * HW * CC;
    const float* offp = offset + (size_t)b * (2 * KK) * HW + rem;
    const float* mp   = mask + (size_t)b * KK * HW + rem;

    // ---- preload all offset/mask scalars (27 loads, static indices) ----
    float offy[KK], offx[KK], msk[KK];
#pragma unroll
    for (int k = 0; k < KK; ++k) {
        offy[k] = offp[(2 * k) * HW];
        offx[k] = offp[(2 * k + 1) * HW];
        msk[k]  = mp[k * HW];
    }

    f32x4 acc[4];
#pragma unroll
    for (int nt = 0; nt < 4; ++nt) acc[nt] = (f32x4){0.f, 0.f, 0.f, 0.f};

    // ---- 3-deep gather ring (all indices compile-time after unroll) ----
    bf16x8 g0[3], g1[3], g2[3], g3[3];  // [slot] corner values
    float  rw0[3], rw1[3], rw2[3], rw3[3];

#define ISSUE_TAP(k_, s_)                                                     \
    {                                                                         \
        float py = offy[k_] + (float)((k_) / KHW) + (float)(ho - 1);          \
        float px = offx[k_] + (float)((k_) % KHW) + (float)(wo - 1);          \
        float fy0 = floorf(py), fx0 = floorf(px);                             \
        float ly = py - fy0, lx = px - fx0;                                   \
        int y0 = (int)fy0, x0 = (int)fx0;                                     \
        int y1 = y0 + 1, x1 = x0 + 1;                                         \
        bool vy0 = (y0 >= 0) && (y0 < HH);                                    \
        bool vy1 = (y1 >= 0) && (y1 < HH);                                    \
        bool vx0 = (x0 >= 0) && (x0 < WW);                                    \
        bool vx1 = (x1 >= 0) && (x1 < WW);                                    \
        int cy0 = min(max(y0, 0), HH - 1), cy1 = min(max(y1, 0), HH - 1);     \
        int cx0 = min(max(x0, 0), WW - 1), cx1 = min(max(x1, 0), WW - 1);     \
        float mmv = msk[k_];                                                  \
        rw0[s_] = (vy0 && vx0) ? mmv * (1.0f - ly) * (1.0f - lx) : 0.0f;      \
        rw1[s_] = (vy0 && vx1) ? mmv * (1.0f - ly) * lx : 0.0f;               \
        rw2[s_] = (vy1 && vx0) ? mmv * ly * (1.0f - lx) : 0.0f;               \
        rw3[s_] = (vy1 && vx1) ? mmv * ly * lx : 0.0f;                        \
        g0[s_] = *(const bf16x8*)(xb + (size_t)(cy0 * WW + cx0) * CC + cb);   \
        g1[s_] = *(const bf16x8*)(xb + (size_t)(cy0 * WW + cx1) * CC + cb);   \
        g2[s_] = *(const bf16x8*)(xb + (size_t)(cy1 * WW + cx0) * CC + cb);   \
        g3[s_] = *(const bf16x8*)(xb + (size_t)(cy1 * WW + cx1) * CC + cb);   \
    }

    ISSUE_TAP(0, 0)
    ISSUE_TAP(1, 1)
    ISSUE_TAP(2, 2)

#pragma unroll
    for (int k = 0; k < KK; ++k) {
        const int s = k % 3;

        // ---- blend slot s (tap k) -> A fragment: consume BEFORE reuse ----
        bf16x8 af;
        {
            float w0 = rw0[s], w1 = rw1[s], w2 = rw2[s], w3 = rw3[s];
            bf16x8 a00 = g0[s], a01 = g1[s], a10 = g2[s], a11 = g3[s];
#pragma unroll
            for (int i = 0; i < 8; ++i) {
                float v = w0 * (float)a00[i] + w1 * (float)a01[i] +
                          w2 * (float)a10[i] + w3 * (float)a11[i];
                af[i] = (bf16_t)v;
            }
        }

        // ---- slot s now free: issue tap k+3 into it ----
        if (k + 3 < KK) {
            switch (k + 3) {  // unrolled: constant k makes this a single arm
                case 3: ISSUE_TAP(3, s) break;
                case 4: ISSUE_TAP(4, s) break;
                case 5: ISSUE_TAP(5, s) break;
                case 6: ISSUE_TAP(6, s) break;
                case 7: ISSUE_TAP(7, s) break;
                case 8: ISSUE_TAP(8, s) break;
            }
        }

        // ---- MFMA: 16 pixels x 64 outputs, this wave's K=32 half ----
#pragma unroll
        for (int nt = 0; nt < 4; ++nt) {
            bf16x8 bfg = wf[((k * 2 + q) * 4 + nt) * 64 + lane];
            acc[nt] = __builtin_amdgcn_mfma_f32_16x16x32_bf16(
                af, bfg, acc[nt], 0, 0, 0);
        }
    }
#undef ISSUE_TAP

    // ---- pairwise K-half reduction through LDS, then epilogue ----
    __shared__ f32x4 red[4][64][4];   // 16 KB
    if (q) {
#pragma unroll
        for (int nt = 0; nt < 4; ++nt) red[strip][lane][nt] = acc[nt];
    }
    __syncthreads();
    if (!q) {
#pragma unroll
        for (int nt = 0; nt < 4; ++nt) {
            int o = nt * 16 + col;
            float bv = bias[o];
            f32x4 r = acc[nt] + red[strip][lane][nt];
            r.x += bv; r.y += bv; r.z += bv; r.w += bv;
            // D[row=quad*4+reg][col]; row -> pixel, col -> output
            float* dst = out + (size_t)(b * OO + o) * HW + p0 + m0 + quad * 4;
            *(f32x4*)dst = r;  // 4 consecutive pixels, 16B aligned
        }
    }
}

extern "C" void kernel_launch(void* const* d_in, const int* in_sizes, int n_in,
                              void* d_out, int out_size, void* d_ws,
                              size_t ws_size, hipStream_t stream) {
    const float* x      = (const float*)d_in[0];
    const float* offset = (const float*)d_in[1];
    const float* mask   = (const float*)d_in[2];
    const float* weight = (const float*)d_in[3];
    const float* bias   = (const float*)d_in[4];
    float* out = (float*)d_out;

    bf16_t* xt  = (bf16_t*)d_ws;                       // 4*16384*64*2 = 8 MB
    bf16_t* wfr = (bf16_t*)((char*)d_ws + (size_t)BB * HW * CC * 2);  // 72 KB

    int nwf_blocks = (OO * CC * KK + 255) / 256;       // 144
    prep_kernel<<<BB * 256 + nwf_blocks, 256, 0, stream>>>(x, xt, weight, wfr);

    deform_conv_mfma<<<BB * (HW / 64), 512, 0, stream>>>(
        xt, offset, mask, (const bf16x8*)wfr, bias, out);
}

// Round 5
// 121.525 us; speedup vs baseline: 1.2018x; 1.2018x over previous
//
#include <hip/hip_runtime.h>

// Modulated deformable conv2d, fp32 in/out, bf16 MFMA core.
// B=4, C=64, H=W=128, O=64, K=3x3, stride=1, pad=1, dil=1, og=1, groups=1.
//
// Round 10: retry the MLP experiment without the round-9 scratch spill
// (r9: switch-in-unrolled-loop kept arrays runtime-indexed -> VGPR 64 +
// 76 MB scratch traffic; rule #20). Depth-2 software pipeline with NAMED
// parity register sets (A/B), 9 explicitly expanded tap bodies:
//   iter k: ISSUE(k+1, other-parity) -> roll scalars (k+2) -> BLEND(k) ->
//   8x MFMA. 8-16 gathers in flight during all compute (round 6: 8 only
//   during an exposed wait). Round-6 wave structure (16 px, full K=64,
//   no LDS/barriers), XCD-aware swizzle kept. __launch_bounds__(256,4).
// Fragment layouts (m89/m120-verified): A[m=lane&15][k=quad*8+j],
// B[k=quad*8+j][n=lane&15], D[row=quad*4+reg][col=lane&15].

#define BB 4
#define CC 64
#define HH 128
#define WW 128
#define OO 64
#define KHW 3
#define KK 9
#define HW (HH * WW)

typedef __bf16 bf16_t;
typedef bf16_t bf16x8 __attribute__((ext_vector_type(8)));
typedef float f32x4 __attribute__((ext_vector_type(4)));

// ---- prep: x (NCHW fp32) -> xt (NHWC bf16)  +  weight -> B-fragment bf16 ----
__global__ __launch_bounds__(256) void prep_kernel(const float* __restrict__ x,
                                                   bf16_t* __restrict__ xt,
                                                   const float* __restrict__ w,
                                                   bf16_t* __restrict__ wf) {
    __shared__ float tile[64 * 65];
    const int t = threadIdx.x;
    if (blockIdx.x < BB * 256) {
        const int b  = blockIdx.x >> 8;
        const int p0 = (blockIdx.x & 255) << 6;
#pragma unroll
        for (int i = 0; i < 16; ++i) {
            int c = i * 4 + (t >> 6);
            int p = t & 63;
            tile[c * 65 + p] = x[(b * CC + c) * HW + p0 + p];  // coalesced
        }
        __syncthreads();
#pragma unroll
        for (int i = 0; i < 16; ++i) {
            int p = i * 4 + (t >> 6);
            int c = t & 63;
            xt[(size_t)((b * HW) + p0 + p) * CC + c] = (bf16_t)tile[c * 65 + p];
        }
    } else {
        // wf element index: ((tap*2+q)*4+nt)*64*8 + lane*8 + j
        //   holds W[o = nt*16 + (lane&15)][c = q*32 + (lane>>4)*8 + j][tap]
        int i = (blockIdx.x - BB * 256) * 256 + t;
        if (i >= OO * CC * KK) return;
        int j    = i & 7;
        int lane = (i >> 3) & 63;
        int nt   = (i >> 9) & 3;
        int q    = (i >> 11) & 1;
        int k    = i >> 12;
        int o = nt * 16 + (lane & 15);
        int c = q * 32 + ((lane >> 4) << 3) + j;
        wf[i] = (bf16_t)w[(o * CC + c) * KK + k];
    }
}

__global__ __launch_bounds__(256, 4) void deform_conv_mfma(
    const bf16_t* __restrict__ xt, const float* __restrict__ offset,
    const float* __restrict__ mask, const bf16x8* __restrict__ wf,
    const float* __restrict__ bias, float* __restrict__ out) {
    const int t    = threadIdx.x;
    // XCD-aware bijective swizzle: grid = 1024 = 8 * 128.
    const int wg   = (blockIdx.x & 7) * ((BB * 256) >> 3) + (blockIdx.x >> 3);
    const int b    = wg >> 8;
    const int p0   = (wg & 255) << 6;          // 64-pixel group
    const int lane = t & 63;
    const int wv   = t >> 6;
    const int m0   = wv << 4;                  // wave's 16-pixel strip
    const int col  = lane & 15;                // A-row m == pixel in strip
    const int quad = lane >> 4;
    const int rem  = p0 + m0 + col;            // this lane's pixel
    const int ho   = rem >> 7;
    const int wo   = rem & (WW - 1);
    const int cb   = quad << 3;                // channel sub-offset quad*8
    const float fho = (float)(ho - 1);
    const float fwo = (float)(wo - 1);

    const bf16_t* xb  = xt + (size_t)b * HW * CC;
    const float* offp = offset + (size_t)b * (2 * KK) * HW + rem;
    const float* mp   = mask + (size_t)b * KK * HW + rem;

    f32x4 acc[4];
#pragma unroll
    for (int nt = 0; nt < 4; ++nt) acc[nt] = (f32x4){0.f, 0.f, 0.f, 0.f};

    // ---- named depth-2 pipeline state (NO arrays -> no scratch) ----
    float syA, sxA, smA, syB, sxB, smB;             // scalars, parity-rolled
    float wA0, wA1, wA2, wA3, wB0, wB1, wB2, wB3;   // corner weights
    bf16x8 gA00, gA01, gA10, gA11, hA00, hA01, hA10, hA11;  // tap even
    bf16x8 gB00, gB01, gB10, gB11, hB00, hB01, hB10, hB11;  // tap odd
    bf16x8 af0, af1;

#define LOADS(k_, P_)                                                         \
    if ((k_) < KK) {                                                          \
        sy##P_ = offp[(2 * (k_)) * HW];                                       \
        sx##P_ = offp[(2 * (k_) + 1) * HW];                                   \
        sm##P_ = mp[(k_) * HW];                                               \
    }

#define ISSUE(k_, P_)                                                         \
    {                                                                         \
        float py = sy##P_ + (float)((k_) / KHW) + fho;                        \
        float px = sx##P_ + (float)((k_) % KHW) + fwo;                        \
        float fy0 = floorf(py), fx0 = floorf(px);                             \
        float ly = py - fy0, lx = px - fx0;                                   \
        int y0 = (int)fy0, x0 = (int)fx0;                                     \
        int y1 = y0 + 1, x1 = x0 + 1;                                         \
        bool vy0 = (y0 >= 0) && (y0 < HH), vy1 = (y1 >= 0) && (y1 < HH);      \
        bool vx0 = (x0 >= 0) && (x0 < WW), vx1 = (x1 >= 0) && (x1 < WW);      \
        int cy0 = min(max(y0, 0), HH - 1), cy1 = min(max(y1, 0), HH - 1);     \
        int cx0 = min(max(x0, 0), WW - 1), cx1 = min(max(x1, 0), WW - 1);     \
        float mmv = sm##P_;                                                   \
        w##P_##0 = (vy0 && vx0) ? mmv * (1.0f - ly) * (1.0f - lx) : 0.0f;     \
        w##P_##1 = (vy0 && vx1) ? mmv * (1.0f - ly) * lx : 0.0f;              \
        w##P_##2 = (vy1 && vx0) ? mmv * ly * (1.0f - lx) : 0.0f;              \
        w##P_##3 = (vy1 && vx1) ? mmv * ly * lx : 0.0f;                       \
        const bf16_t* b00 = xb + (size_t)(cy0 * WW + cx0) * CC + cb;          \
        const bf16_t* b01 = xb + (size_t)(cy0 * WW + cx1) * CC + cb;          \
        const bf16_t* b10 = xb + (size_t)(cy1 * WW + cx0) * CC + cb;          \
        const bf16_t* b11 = xb + (size_t)(cy1 * WW + cx1) * CC + cb;          \
        g##P_##00 = *(const bf16x8*)b00; h##P_##00 = *(const bf16x8*)(b00 + 32); \
        g##P_##01 = *(const bf16x8*)b01; h##P_##01 = *(const bf16x8*)(b01 + 32); \
        g##P_##10 = *(const bf16x8*)b10; h##P_##10 = *(const bf16x8*)(b10 + 32); \
        g##P_##11 = *(const bf16x8*)b11; h##P_##11 = *(const bf16x8*)(b11 + 32); \
    }

#define BLEND(P_)                                                             \
    {                                                                         \
        _Pragma("unroll") for (int i = 0; i < 8; ++i) {                       \
            float v = w##P_##0 * (float)g##P_##00[i] +                        \
                      w##P_##1 * (float)g##P_##01[i] +                        \
                      w##P_##2 * (float)g##P_##10[i] +                        \
                      w##P_##3 * (float)g##P_##11[i];                         \
            af0[i] = (bf16_t)v;                                               \
        }                                                                     \
        _Pragma("unroll") for (int i = 0; i < 8; ++i) {                       \
            float v = w##P_##0 * (float)h##P_##00[i] +                        \
                      w##P_##1 * (float)h##P_##01[i] +                        \
                      w##P_##2 * (float)h##P_##10[i] +                        \
                      w##P_##3 * (float)h##P_##11[i];                         \
            af1[i] = (bf16_t)v;                                               \
        }                                                                     \
    }

#define MFMAS(k_)                                                             \
    {                                                                         \
        _Pragma("unroll") for (int nt = 0; nt < 4; ++nt) {                    \
            bf16x8 bfg = wf[((k_) * 8 + nt) * 64 + lane];                     \
            acc[nt] = __builtin_amdgcn_mfma_f32_16x16x32_bf16(                \
                af0, bfg, acc[nt], 0, 0, 0);                                  \
        }                                                                     \
        _Pragma("unroll") for (int nt = 0; nt < 4; ++nt) {                    \
            bf16x8 bfg = wf[((k_) * 8 + 4 + nt) * 64 + lane];                 \
            acc[nt] = __builtin_amdgcn_mfma_f32_16x16x32_bf16(                \
                af1, bfg, acc[nt], 0, 0, 0);                                  \
        }                                                                     \
    }

// iter k (parity P_ holds tap k): issue k+1 into Q_, roll scalars k+2 into
// P_'s slots (dead after ISSUE(k) last iter), blend k, MFMA k.
#define BODY(k_, P_, Q_)                                                      \
    {                                                                         \
        if ((k_) + 1 < KK) ISSUE((k_) + 1, Q_);                               \
        LOADS((k_) + 2, P_);                                                  \
        BLEND(P_);                                                            \
        MFMAS(k_);                                                            \
    }

    LOADS(0, A)
    LOADS(1, B)
    ISSUE(0, A);

    BODY(0, A, B)
    BODY(1, B, A)
    BODY(2, A, B)
    BODY(3, B, A)
    BODY(4, A, B)
    BODY(5, B, A)
    BODY(6, A, B)
    BODY(7, B, A)
    BODY(8, A, B)

#undef BODY
#undef MFMAS
#undef BLEND
#undef ISSUE
#undef LOADS

    // ---- epilogue: D[row=quad*4+reg][col] ; row -> pixel, col -> output ----
#pragma unroll
    for (int nt = 0; nt < 4; ++nt) {
        int o = nt * 16 + col;
        float bv = bias[o];
        f32x4 r = acc[nt];
        r.x += bv; r.y += bv; r.z += bv; r.w += bv;
        float* dst = out + (size_t)(b * OO + o) * HW + p0 + m0 + quad * 4;
        *(f32x4*)dst = r;  // 4 consecutive pixels, 16B aligned
    }
}

extern "C" void kernel_launch(void* const* d_in, const int* in_sizes, int n_in,
                              void* d_out, int out_size, void* d_ws,
                              size_t ws_size, hipStream_t stream) {
    const float* x      = (const float*)d_in[0];
    const float* offset = (const float*)d_in[1];
    const float* mask   = (const float*)d_in[2];
    const float* weight = (const float*)d_in[3];
    const float* bias   = (const float*)d_in[4];
    float* out = (float*)d_out;

    bf16_t* xt  = (bf16_t*)d_ws;                       // 4*16384*64*2 = 8 MB
    bf16_t* wfr = (bf16_t*)((char*)d_ws + (size_t)BB * HW * CC * 2);  // 72 KB

    int nwf_blocks = (OO * CC * KK + 255) / 256;       // 144
    prep_kernel<<<BB * 256 + nwf_blocks, 256, 0, stream>>>(x, xt, weight, wfr);

    deform_conv_mfma<<<BB * (HW / 64), 256, 0, stream>>>(
        xt, offset, mask, (const bf16x8*)wfr, bias, out);
}

// Round 6
// 100.087 us; speedup vs baseline: 1.4592x; 1.2142x over previous
//
#include <hip/hip_runtime.h>

// Modulated deformable conv2d, fp32 in/out, bf16 MFMA core.
// B=4, C=64, H=W=128, O=64, K=3x3, stride=1, pad=1, dil=1, og=1, groups=1.
//
// Round 11: L1-miss-throughput fix. Rounds 5/6/7/10 all land at ~50 us while
// FETCH varied 29->8 MB and occupancy 2x: the invariant is ~4.7M L1 misses
// (gather stream 302 MB >> 32 KB L1) at ~32 MSHR/CU x ~220 cyc L2 latency
// ~= 53 us. Fix: capture the 38x gather reuse in LDS.
//  - Block = 8x8 output tile; stage its 16x16-px window (32 KB bf16 NHWC)
//    once (clamped, coalesced), ONE barrier, 9 taps gather from LDS.
//  - Covers |off|<=3; rarer samples (P~0.3%, only when weight!=0) fall back
//    to per-lane global loads in an exec-masked, almost-always-skipped branch.
//  - Chunk-XOR swizzle slot^=(px&7) on write+read kills the 128B-stride
//    16-way bank conflict (pixel stride = 32 banks).
//  - 4 blocks/CU (128 KB LDS), __launch_bounds__(256,4), XCD swizzle kept.
// Fragment layouts (m89/m120-verified): A[m=lane&15][k=quad*8+j],
// B[k=quad*8+j][n=lane&15], D[row=quad*4+reg][col=lane&15].

#define BB 4
#define CC 64
#define HH 128
#define WW 128
#define OO 64
#define KHW 3
#define KK 9
#define HW (HH * WW)

typedef __bf16 bf16_t;
typedef bf16_t bf16x8 __attribute__((ext_vector_type(8)));
typedef float f32x4 __attribute__((ext_vector_type(4)));

// ---- prep: x (NCHW fp32) -> xt (NHWC bf16)  +  weight -> B-fragment bf16 ----
__global__ __launch_bounds__(256) void prep_kernel(const float* __restrict__ x,
                                                   bf16_t* __restrict__ xt,
                                                   const float* __restrict__ w,
                                                   bf16_t* __restrict__ wf) {
    __shared__ float tile[64 * 65];
    const int t = threadIdx.x;
    if (blockIdx.x < BB * 256) {
        const int b  = blockIdx.x >> 8;
        const int p0 = (blockIdx.x & 255) << 6;
#pragma unroll
        for (int i = 0; i < 16; ++i) {
            int c = i * 4 + (t >> 6);
            int p = t & 63;
            tile[c * 65 + p] = x[(b * CC + c) * HW + p0 + p];  // coalesced
        }
        __syncthreads();
#pragma unroll
        for (int i = 0; i < 16; ++i) {
            int p = i * 4 + (t >> 6);
            int c = t & 63;
            xt[(size_t)((b * HW) + p0 + p) * CC + c] = (bf16_t)tile[c * 65 + p];
        }
    } else {
        // wf element index: ((tap*2+q)*4+nt)*64*8 + lane*8 + j
        //   holds W[o = nt*16 + (lane&15)][c = q*32 + (lane>>4)*8 + j][tap]
        int i = (blockIdx.x - BB * 256) * 256 + t;
        if (i >= OO * CC * KK) return;
        int j    = i & 7;
        int lane = (i >> 3) & 63;
        int nt   = (i >> 9) & 3;
        int q    = (i >> 11) & 1;
        int k    = i >> 12;
        int o = nt * 16 + (lane & 15);
        int c = q * 32 + ((lane >> 4) << 3) + j;
        wf[i] = (bf16_t)w[(o * CC + c) * KK + k];
    }
}

__global__ __launch_bounds__(256, 4) void deform_conv_mfma(
    const bf16_t* __restrict__ xt, const float* __restrict__ offset,
    const float* __restrict__ mask, const bf16x8* __restrict__ wf,
    const float* __restrict__ bias, float* __restrict__ out) {
    const int t    = threadIdx.x;
    // XCD-aware bijective swizzle: grid = 1024 = 8 * 128.
    const int wg   = (blockIdx.x & 7) * ((BB * 256) >> 3) + (blockIdx.x >> 3);
    const int b    = wg >> 8;
    const int ti   = wg & 255;                 // tile id: 16x16 tiles of 8x8
    const int r0   = ((ti >> 4) << 3);         // tile top row
    const int c0   = ((ti & 15) << 3);         // tile left col
    const int lane = t & 63;
    const int wv   = t >> 6;                   // wave: rows 2wv, 2wv+1
    const int col  = lane & 15;                // A-row m == pixel in wave
    const int quad = lane >> 4;
    const int prow = r0 + 2 * wv + (col >> 3); // this lane's pixel row
    const int pcol = c0 + (col & 7);
    const int rem  = prow * WW + pcol;
    const int wy0  = r0 - 4;                   // window origin (16x16 px)
    const int wx0  = c0 - 4;
    const int cb   = quad << 3;                // lane's 8-ch slot base

    __shared__ bf16_t V[256 * 64];             // 32 KB swizzled window

    const bf16_t* xb  = xt + (size_t)b * HW * CC;
    const float* offp = offset + (size_t)b * (2 * KK) * HW + rem;
    const float* mp   = mask + (size_t)b * KK * HW + rem;

    // ---- stage 16x16-pixel window, clamped, chunk-swizzled ----
    {
        const int i  = t >> 4;                 // window row 0..15
        const int j  = t & 15;                 // window col 0..15
        const int cy = min(max(wy0 + i, 0), HH - 1);
        const int cx = min(max(wx0 + j, 0), WW - 1);
        const bf16_t* src = xb + (size_t)(cy * WW + cx) * CC;
        bf16_t* dst = &V[(i * 16 + j) * 64];
        const int sw = (j & 7) * 8;
#pragma unroll
        for (int s = 0; s < 8; ++s)
            *(bf16x8*)(dst + ((s * 8) ^ sw)) = *(const bf16x8*)(src + s * 8);
    }
    __syncthreads();

    f32x4 acc[4];
#pragma unroll
    for (int nt = 0; nt < 4; ++nt) acc[nt] = (f32x4){0.f, 0.f, 0.f, 0.f};

    float offy = offp[0];
    float offx = offp[HW];
    float mm   = mp[0];

#pragma unroll
    for (int k = 0; k < KK; ++k) {
        float n_offy = 0.f, n_offx = 0.f, n_mm = 0.f;
        if (k < KK - 1) {
            n_offy = offp[(2 * k + 2) * HW];
            n_offx = offp[(2 * k + 3) * HW];
            n_mm   = mp[(k + 1) * HW];
        }

        // ---- bilinear setup (exact reference semantics) ----
        float py = offy + (float)(k / KHW) + (float)(prow - 1);
        float px = offx + (float)(k % KHW) + (float)(pcol - 1);
        float fy0 = floorf(py), fx0 = floorf(px);
        float ly = py - fy0, lx = px - fx0;
        int y0 = (int)fy0, x0 = (int)fx0;
        int y1 = y0 + 1, x1 = x0 + 1;
        bool vy0 = (y0 >= 0) && (y0 < HH), vy1 = (y1 >= 0) && (y1 < HH);
        bool vx0 = (x0 >= 0) && (x0 < WW), vx1 = (x1 >= 0) && (x1 < WW);
        int cy0 = min(max(y0, 0), HH - 1), cy1 = min(max(y1, 0), HH - 1);
        int cx0 = min(max(x0, 0), WW - 1), cx1 = min(max(x1, 0), WW - 1);
        float w0 = (vy0 && vx0) ? mm * (1.0f - ly) * (1.0f - lx) : 0.0f;
        float w1 = (vy0 && vx1) ? mm * (1.0f - ly) * lx : 0.0f;
        float w2 = (vy1 && vx0) ? mm * ly * (1.0f - lx) : 0.0f;
        float w3 = (vy1 && vx1) ? mm * ly * lx : 0.0f;

        // ---- window-relative corner coords ----
        int uy0 = y0 - wy0, ux0 = x0 - wx0;
        int uy1 = uy0 + 1,  ux1 = ux0 + 1;
        bool iy0 = (unsigned)uy0 < 16u, iy1 = (unsigned)uy1 < 16u;
        bool ix0 = (unsigned)ux0 < 16u, ix1 = (unsigned)ux1 < 16u;
        int qy0 = min(max(uy0, 0), 15), qy1 = min(max(uy1, 0), 15);
        int qx0 = min(max(ux0, 0), 15), qx1 = min(max(ux1, 0), 15);
        int pa = (qy0 * 16 + qx0) * 64, pb = (qy0 * 16 + qx1) * 64;
        int pc = (qy1 * 16 + qx0) * 64, pd = (qy1 * 16 + qx1) * 64;
        int sa = (qx0 & 7), sb = (qx1 & 7);  // swizzle keys (row-indep)

        // ---- LDS gathers: g = chunk quad (ch cb..cb+7), h = chunk 4+quad ----
        bf16x8 g00 = *(const bf16x8*)&V[pa + ((quad ^ sa) << 3)];
        bf16x8 h00 = *(const bf16x8*)&V[pa + (((4 + quad) ^ sa) << 3)];
        bf16x8 g01 = *(const bf16x8*)&V[pb + ((quad ^ sb) << 3)];
        bf16x8 h01 = *(const bf16x8*)&V[pb + (((4 + quad) ^ sb) << 3)];
        bf16x8 g10 = *(const bf16x8*)&V[pc + ((quad ^ sa) << 3)];
        bf16x8 h10 = *(const bf16x8*)&V[pc + (((4 + quad) ^ sa) << 3)];
        bf16x8 g11 = *(const bf16x8*)&V[pd + ((quad ^ sb) << 3)];
        bf16x8 h11 = *(const bf16x8*)&V[pd + (((4 + quad) ^ sb) << 3)];

        // ---- rare out-of-window fallback (exec-masked, usually skipped) ----
        if (w0 != 0.0f && !(iy0 && ix0)) {
            const bf16_t* p = xb + (size_t)(cy0 * WW + cx0) * CC + cb;
            g00 = *(const bf16x8*)p; h00 = *(const bf16x8*)(p + 32);
        }
        if (w1 != 0.0f && !(iy0 && ix1)) {
            const bf16_t* p = xb + (size_t)(cy0 * WW + cx1) * CC + cb;
            g01 = *(const bf16x8*)p; h01 = *(const bf16x8*)(p + 32);
        }
        if (w2 != 0.0f && !(iy1 && ix0)) {
            const bf16_t* p = xb + (size_t)(cy1 * WW + cx0) * CC + cb;
            g10 = *(const bf16x8*)p; h10 = *(const bf16x8*)(p + 32);
        }
        if (w3 != 0.0f && !(iy1 && ix1)) {
            const bf16_t* p = xb + (size_t)(cy1 * WW + cx1) * CC + cb;
            g11 = *(const bf16x8*)p; h11 = *(const bf16x8*)(p + 32);
        }

        // ---- blend -> A fragments ----
        bf16x8 af0, af1;
#pragma unroll
        for (int i = 0; i < 8; ++i) {
            float v = w0 * (float)g00[i] + w1 * (float)g01[i] +
                      w2 * (float)g10[i] + w3 * (float)g11[i];
            af0[i] = (bf16_t)v;
        }
#pragma unroll
        for (int i = 0; i < 8; ++i) {
            float v = w0 * (float)h00[i] + w1 * (float)h01[i] +
                      w2 * (float)h10[i] + w3 * (float)h11[i];
            af1[i] = (bf16_t)v;
        }

        // ---- MFMA: 16 pixels x 64 outputs, K=64 (one tap) ----
#pragma unroll
        for (int nt = 0; nt < 4; ++nt) {
            bf16x8 bfg = wf[(k * 8 + nt) * 64 + lane];
            acc[nt] = __builtin_amdgcn_mfma_f32_16x16x32_bf16(
                af0, bfg, acc[nt], 0, 0, 0);
        }
#pragma unroll
        for (int nt = 0; nt < 4; ++nt) {
            bf16x8 bfg = wf[(k * 8 + 4 + nt) * 64 + lane];
            acc[nt] = __builtin_amdgcn_mfma_f32_16x16x32_bf16(
                af1, bfg, acc[nt], 0, 0, 0);
        }

        offy = n_offy;
        offx = n_offx;
        mm   = n_mm;
    }

    // ---- epilogue: D[row=quad*4+reg][col]; row -> pixel m, col -> output ----
    // m = quad*4+reg: out row r0+2wv+(quad>>1), cols c0+(quad&1)*4 .. +3.
#pragma unroll
    for (int nt = 0; nt < 4; ++nt) {
        int o = nt * 16 + col;
        float bv = bias[o];
        f32x4 r = acc[nt];
        r.x += bv; r.y += bv; r.z += bv; r.w += bv;
        float* dst = out + (size_t)(b * OO + o) * HW +
                     (r0 + 2 * wv + (quad >> 1)) * WW + c0 + (quad & 1) * 4;
        *(f32x4*)dst = r;  // 4 consecutive pixels, 16B aligned
    }
}

extern "C" void kernel_launch(void* const* d_in, const int* in_sizes, int n_in,
                              void* d_out, int out_size, void* d_ws,
                              size_t ws_size, hipStream_t stream) {
    const float* x      = (const float*)d_in[0];
    const float* offset = (const float*)d_in[1];
    const float* mask   = (const float*)d_in[2];
    const float* weight = (const float*)d_in[3];
    const float* bias   = (const float*)d_in[4];
    float* out = (float*)d_out;

    bf16_t* xt  = (bf16_t*)d_ws;                       // 4*16384*64*2 = 8 MB
    bf16_t* wfr = (bf16_t*)((char*)d_ws + (size_t)BB * HW * CC * 2);  // 72 KB

    int nwf_blocks = (OO * CC * KK + 255) / 256;       // 144
    prep_kernel<<<BB * 256 + nwf_blocks, 256, 0, stream>>>(x, xt, weight, wfr);

    deform_conv_mfma<<<BB * (HW / 64), 256, 0, stream>>>(
        xt, offset, mask, (const bf16x8*)wfr, bias, out);
}